// Round 4
// baseline (269.520 us; speedup 1.0000x reference)
//
#include <hip/hip_runtime.h>
#include <hip/hip_bf16.h>

typedef float f32x4 __attribute__((ext_vector_type(4)));
typedef short bf16x8 __attribute__((ext_vector_type(8)));

#define MFMA16(a, b, c) __builtin_amdgcn_mfma_f32_16x16x32_bf16(a, b, c, 0, 0, 0)

// Problem constants
constexpr int K1      = 940;    // IN_F
constexpr int KP      = 960;    // K padded to mult of 32
constexpr int NP      = 112;    // N=100 padded to 7 tiles of 16
constexpr int OUT1_LD = 128;    // out1 row stride (K for xg GEMM, padded)

__device__ __forceinline__ float sigf(float x) { return 1.f / (1.f + __expf(-x)); }
__device__ __forceinline__ float tanhfast(float x) { return 2.f / (1.f + __expf(-2.f * x)) - 1.f; }

__device__ __forceinline__ short f2b(float x) {
  __hip_bfloat16 b = __float2bfloat16(x);
  return *reinterpret_cast<short*>(&b);
}

// ---------------------------------------------------------------------------
// Prep: fold swapaxes(-1,-2) into the weights, convert fp32->bf16, zero-pad.
// w2[n][k] = bf16(lin_w[n][f]) where k=c10*94+c2*47+c47, f=c10*94+c47*2+c2
// bw2[g][k] = bf16(b_wih[g][k]) zero-padded K 100->128.
// ---------------------------------------------------------------------------
__global__ void prep_kernel(const float* __restrict__ lin_w,
                            const float* __restrict__ b_wih,
                            __hip_bfloat16* __restrict__ w2,
                            __hip_bfloat16* __restrict__ bw2) {
  int idx = blockIdx.x * 256 + threadIdx.x;
  if (idx < NP * KP) {
    int n = idx / KP, k = idx - n * KP;
    float v = 0.f;
    if (n < 100 && k < K1) {
      int c10 = k / 94, rem = k - c10 * 94;
      int c2 = rem / 47, c47 = rem - c2 * 47;
      int f = c10 * 94 + c47 * 2 + c2;
      v = lin_w[n * K1 + f];
    }
    w2[idx] = __float2bfloat16(v);
  } else {
    int i2 = idx - NP * KP;
    if (i2 < 64 * 128) {
      int g = i2 >> 7, k = i2 & 127;
      bw2[i2] = __float2bfloat16((k < 100) ? b_wih[g * 100 + k] : 0.f);
    }
  }
}

// ---------------------------------------------------------------------------
// Phase 1: out1[m][n] = relu(channels[m][:] @ w2[n][:]^T + lin_b[n]).
// Barrier-free software pipeline: no LDS (B fragments straight from L2 —
// w2 is 215 KB and read by every block), A prefetched 2 K-steps ahead
// (HBM ~900 cyc latency; 8 waves/CU x 2 KB x 2-deep = 32 KB in flight),
// B prefetched 1 step ahead (L2 ~300 cyc). Tail step (k=928..939) peeled.
// ---------------------------------------------------------------------------
__global__ __launch_bounds__(256, 2)
void linear_relu_mfma(const float* __restrict__ ch,
                      const __hip_bfloat16* __restrict__ w2,
                      const float* __restrict__ lin_b,
                      __hip_bfloat16* __restrict__ out1) {
  const int tid = threadIdx.x;
  const int wave = tid >> 6, lane = tid & 63;
  const int l16 = lane & 15, bq = lane >> 4;  // A: m=l16, k=bq*8+j ; B: n=l16
  const int m0 = blockIdx.x * 64 + wave * 16;
  const float* arow = ch + (long)(m0 + l16) * K1 + bq * 8;       // +s*32 per step
  const __hip_bfloat16* brow = w2 + l16 * KP + bq * 8;           // +nt*16*KP +s*32

  f32x4 acc[7] = {};

  auto LDA = [&](int s, float4& lo4, float4& hi4) {
    const float* p = arow + s * 32;
    lo4 = *reinterpret_cast<const float4*>(p);
    hi4 = *reinterpret_cast<const float4*>(p + 4);
  };
  auto LDB = [&](int s, bf16x8* bb) {
    const __hip_bfloat16* p = brow + s * 32;
#pragma unroll
    for (int nt = 0; nt < 7; ++nt)
      bb[nt] = *reinterpret_cast<const bf16x8*>(p + nt * 16 * KP);
  };
  auto CVT = [&](float4 lo4, float4 hi4) -> bf16x8 {
    return bf16x8{f2b(lo4.x), f2b(lo4.y), f2b(lo4.z), f2b(lo4.w),
                  f2b(hi4.x), f2b(hi4.y), f2b(hi4.z), f2b(hi4.w)};
  };
  auto STEP = [&](bf16x8 a, bf16x8* bb) {
#pragma unroll
    for (int nt = 0; nt < 7; ++nt) acc[nt] = MFMA16(a, bb[nt], acc[nt]);
  };

  // prologue: A(0), A(1), B(0) in flight
  float4 l0, h0, l1, h1;
  bf16x8 b0[7], b1[7];
  LDA(0, l0, h0);
  LDA(1, l1, h1);
  LDB(0, b0);

  // steady state: steps 0..27 (14 x 2), prefetch A(s+2)/B(s+1)
  for (int s = 0; s < 28; s += 2) {
    bf16x8 a0 = CVT(l0, h0);
    LDA(s + 2, l0, h0);          // A(s+2), max A(28): k 896..927, in-bounds
    LDB(s + 1, b1);
    STEP(a0, b0);
    bf16x8 a1 = CVT(l1, h1);
    if (s < 26) LDA(s + 3, l1, h1);  // A(s+3) <= A(28); A(29) would read OOB
    LDB(s + 2, b0);              // B(s+2) <= B(28)
    STEP(a1, b1);
  }
  // step 28
  {
    bf16x8 a = CVT(l0, h0);
    LDB(29, b1);                 // safe: w2 zero-padded to KP=960
    STEP(a, b0);
  }
  // step 29 (tail, k=928..939): masked scalar A loads, zero beyond K1
  {
    bf16x8 a;
#pragma unroll
    for (int j = 0; j < 8; ++j)
      a[j] = (928 + bq * 8 + j < K1) ? f2b(arow[928 + j]) : short(0);
    STEP(a, b1);
  }

  // Epilogue: C/D layout col=lane&15 (=n), row=(lane>>4)*4+r (=m within tile)
  const int mb = m0 + bq * 4;
#pragma unroll
  for (int nt = 0; nt < 7; ++nt) {
    const int n = nt * 16 + l16;
    const float bias = (n < 100) ? lin_b[n] : 0.f;
#pragma unroll
    for (int r = 0; r < 4; ++r) {
      float v = fmaxf(acc[nt][r] + bias, 0.f);
      out1[(mb + r) * OUT1_LD + n] = __float2bfloat16((n < 100) ? v : 0.f);
    }
  }
#pragma unroll
  for (int r = 0; r < 4; ++r)  // zero pad cols 112..127 (K-pad for xg GEMM)
    out1[(mb + r) * OUT1_LD + 112 + l16] = __float2bfloat16(0.f);
}

// ---------------------------------------------------------------------------
// Phase 2a: xg[m][g] = out1[m][:] @ bw2[g][:]^T + (b_bih[g]+b_bhh[g]), fp32.
// K=128 (zero padded), 4 N-tiles, weights straight from L2 (16 KB).
// ---------------------------------------------------------------------------
__global__ __launch_bounds__(256)
void xg_mfma(const __hip_bfloat16* __restrict__ out1,
             const __hip_bfloat16* __restrict__ bw2,
             const float* __restrict__ bih,
             const float* __restrict__ bhh,
             float* __restrict__ xg) {
  const int tid = threadIdx.x;
  const int wave = tid >> 6, lane = tid & 63;
  const int l16 = lane & 15, bq = lane >> 4;
  const int m0 = blockIdx.x * 64 + wave * 16;
  const int arow = (m0 + l16) * OUT1_LD;
  f32x4 acc[4] = {};
#pragma unroll
  for (int s = 0; s < 4; ++s) {
    const int k0 = s * 32;
    bf16x8 a = *reinterpret_cast<const bf16x8*>(&out1[arow + k0 + bq * 8]);
#pragma unroll
    for (int nt = 0; nt < 4; ++nt) {
      bf16x8 b = *reinterpret_cast<const bf16x8*>(&bw2[(nt * 16 + l16) * 128 + k0 + bq * 8]);
      acc[nt] = MFMA16(a, b, acc[nt]);
    }
  }
  const int mb = m0 + bq * 4;
#pragma unroll
  for (int nt = 0; nt < 4; ++nt) {
    const int g = nt * 16 + l16;
    const float bias = bih[g] + bhh[g];
#pragma unroll
    for (int r = 0; r < 4; ++r) xg[(mb + r) * 64 + g] = acc[nt][r] + bias;
  }
}

// ---------------------------------------------------------------------------
// Phase 2b: beats LSTM. 4096 seqs, T=8, H=16. Block = 4 seqs x 64 gate-threads.
// Gate order i,f,g,o (PyTorch). fp32 recurrence; fp32 stores to d_out.
// ---------------------------------------------------------------------------
__global__ __launch_bounds__(256)
void beats_lstm(const float* __restrict__ xg,
                const float* __restrict__ whh,
                float* __restrict__ beats) {
  const int tid = threadIdx.x;
  const int sl = tid >> 6, j = tid & 63;
  const int seq = blockIdx.x * 4 + sl;
  __shared__ float hbuf[4][16];
  __shared__ float gact[4][64];
  float wr[16];
#pragma unroll
  for (int u = 0; u < 16; ++u) wr[u] = whh[j * 16 + u];
  float c = 0.f;
  if (j < 16) hbuf[sl][j] = 0.f;
  __syncthreads();
  const float* xs = xg + seq * 8 * 64;
  for (int t = 0; t < 8; ++t) {
    float pre = xs[t * 64 + j];
#pragma unroll
    for (int u = 0; u < 16; ++u) pre += wr[u] * hbuf[sl][u];
    gact[sl][j] = (j >= 32 && j < 48) ? tanhfast(pre) : sigf(pre);
    __syncthreads();
    if (j < 16) {
      c = gact[sl][16 + j] * c + gact[sl][j] * gact[sl][32 + j];
      float hn = gact[sl][48 + j] * tanhfast(c);
      hbuf[sl][j] = hn;
      beats[seq * 128 + t * 16 + j] = hn;
    }
    __syncthreads();
  }
}

// ---------------------------------------------------------------------------
// Phase 3: bars biLSTM. 1024 seqs, T=4(beats), H=32. Block = 1 seq,
// 256 threads = 2 dirs x 128 gates. Reads last-frac beats h from d_out (fp32).
// fwd half -> cols 0..31, bwd half -> cols 32..63 (concat order).
// ---------------------------------------------------------------------------
__global__ __launch_bounds__(256)
void bars_bilstm(const float* __restrict__ fwih, const float* __restrict__ fwhh,
                 const float* __restrict__ fbih, const float* __restrict__ fbhh,
                 const float* __restrict__ rwih, const float* __restrict__ rwhh,
                 const float* __restrict__ rbih, const float* __restrict__ rbhh,
                 const float* __restrict__ beats,
                 float* __restrict__ bars) {
  const int tid = threadIdx.x;
  const int dir = tid >> 7, g = tid & 127;
  const int n = blockIdx.x;
  const float* wih = dir ? rwih : fwih;
  const float* whh = dir ? rwhh : fwhh;
  const float bias = dir ? (rbih[g] + rbhh[g]) : (fbih[g] + fbhh[g]);
  float wi[16], wh[32];
#pragma unroll
  for (int u = 0; u < 16; ++u) wi[u] = wih[g * 16 + u];
#pragma unroll
  for (int u = 0; u < 32; ++u) wh[u] = whh[g * 32 + u];
  __shared__ float xbuf[2][16];
  __shared__ float hbuf[2][32];
  __shared__ float gact[2][128];
  float c = 0.f;
  if (g < 32) hbuf[dir][g] = 0.f;
  __syncthreads();
  for (int t = 0; t < 4; ++t) {
    const int tt = dir ? (3 - t) : t;
    if (g < 16) xbuf[dir][g] = beats[((n * 4 + tt) * 8 + 7) * 16 + g];
    __syncthreads();
    float pre = bias;
#pragma unroll
    for (int u = 0; u < 16; ++u) pre += wi[u] * xbuf[dir][u];
#pragma unroll
    for (int u = 0; u < 32; ++u) pre += wh[u] * hbuf[dir][u];
    gact[dir][g] = (g >= 64 && g < 96) ? tanhfast(pre) : sigf(pre);
    __syncthreads();
    if (g < 32) {
      c = gact[dir][32 + g] * c + gact[dir][g] * gact[dir][64 + g];
      float hn = gact[dir][96 + g] * tanhfast(c);
      hbuf[dir][g] = hn;
      bars[(n * 4 + tt) * 64 + dir * 32 + g] = hn;
    }
    __syncthreads();
  }
}

extern "C" void kernel_launch(void* const* d_in, const int* in_sizes, int n_in,
                              void* d_out, int out_size, void* d_ws, size_t ws_size,
                              hipStream_t stream) {
  const float* ch    = (const float*)d_in[0];
  const float* lin_w = (const float*)d_in[1];
  const float* lin_b = (const float*)d_in[2];
  const float* b_wih = (const float*)d_in[3];
  const float* b_whh = (const float*)d_in[4];
  const float* b_bih = (const float*)d_in[5];
  const float* b_bhh = (const float*)d_in[6];
  const float* f_wih = (const float*)d_in[7];
  const float* f_whh = (const float*)d_in[8];
  const float* f_bih = (const float*)d_in[9];
  const float* f_bhh = (const float*)d_in[10];
  const float* r_wih = (const float*)d_in[11];
  const float* r_whh = (const float*)d_in[12];
  const float* r_bih = (const float*)d_in[13];
  const float* r_bhh = (const float*)d_in[14];

  char* ws = (char*)d_ws;
  __hip_bfloat16* w2   = (__hip_bfloat16*)ws;             // 112*960*2   = 215040 B
  __hip_bfloat16* bw2  = (__hip_bfloat16*)(ws + 215040);  // 64*128*2    = 16384 B
  __hip_bfloat16* out1 = (__hip_bfloat16*)(ws + 231424);  // 32768*128*2 = 8388608 B
  float*          xg   = (float*)(ws + 8620032);          // 32768*64*4  = 8388608 B
  float*          out  = (float*)d_out;

  prep_kernel<<<452, 256, 0, stream>>>(lin_w, b_wih, w2, bw2);
  linear_relu_mfma<<<512, 256, 0, stream>>>(ch, w2, lin_b, out1);
  xg_mfma<<<512, 256, 0, stream>>>(out1, bw2, b_bih, b_bhh, xg);
  beats_lstm<<<1024, 256, 0, stream>>>(xg, b_whh, out);
  bars_bilstm<<<1024, 256, 0, stream>>>(f_wih, f_whh, f_bih, f_bhh,
                                        r_wih, r_whh, r_bih, r_bhh,
                                        out, out + 524288);
}

// Round 5
// 244.331 us; speedup vs baseline: 1.1031x; 1.1031x over previous
//
#include <hip/hip_runtime.h>
#include <hip/hip_bf16.h>

typedef float f32x4 __attribute__((ext_vector_type(4)));
typedef short bf16x8 __attribute__((ext_vector_type(8)));

#define MFMA16(a, b, c) __builtin_amdgcn_mfma_f32_16x16x32_bf16(a, b, c, 0, 0, 0)

// Problem constants
constexpr int K1      = 940;    // IN_F
constexpr int KP2     = 1024;   // K padded to 8 chunks of 128
constexpr int NP      = 112;    // N=100 padded to 7 tiles of 16
constexpr int OUT1_LD = 128;    // out1 row stride (K for xg GEMM, padded)

__device__ __forceinline__ float sigf(float x) { return 1.f / (1.f + __expf(-x)); }
__device__ __forceinline__ float tanhfast(float x) { return 2.f / (1.f + __expf(-2.f * x)) - 1.f; }

__device__ __forceinline__ short f2b(float x) {
  __hip_bfloat16 b = __float2bfloat16(x);
  return *reinterpret_cast<short*>(&b);
}

// ---------------------------------------------------------------------------
// Prep: fold swapaxes(-1,-2) into the weights, convert fp32->bf16, zero-pad.
// w2[n][k] (n<112, k<1024) = bf16(lin_w[n][f]), k=c10*94+c2*47+c47,
// f=c10*94+c47*2+c2; zero outside n<100,k<940.
// bw2[g][k] = bf16(b_wih[g][k]) zero-padded K 100->128.
// ---------------------------------------------------------------------------
__global__ void prep_kernel(const float* __restrict__ lin_w,
                            const float* __restrict__ b_wih,
                            __hip_bfloat16* __restrict__ w2,
                            __hip_bfloat16* __restrict__ bw2) {
  int idx = blockIdx.x * 256 + threadIdx.x;
  if (idx < NP * KP2) {
    int n = idx >> 10, k = idx & 1023;
    float v = 0.f;
    if (n < 100 && k < K1) {
      int c10 = k / 94, rem = k - c10 * 94;
      int c2 = rem / 47, c47 = rem - c2 * 47;
      int f = c10 * 94 + c47 * 2 + c2;
      v = lin_w[n * K1 + f];
    }
    w2[idx] = __float2bfloat16(v);
  } else {
    int i2 = idx - NP * KP2;
    if (i2 < 64 * 128) {
      int g = i2 >> 7, k = i2 & 127;
      bw2[i2] = __float2bfloat16((k < 100) ? b_wih[g * 100 + k] : 0.f);
    }
  }
}

// ---------------------------------------------------------------------------
// Phase 1: out1 = relu(channels @ w2^T + lin_b). Split-K-8, B-in-registers.
// Block = 8 waves; wave w owns K-chunk [w*128, w*128+128) with its 28
// B-fragments preloaded in registers (112 VGPRs) -> NO B traffic, NO LDS, NO
// barriers in the MFMA loop. Per 16-row M-tile: 8 batched float4 A-loads,
// 28 MFMAs, LDS split-K reduction (8x16x112 fp32), bias+relu+bf16 store.
// Next tile's A is issued before the reduction so it flies during it.
// ---------------------------------------------------------------------------
__global__ __launch_bounds__(512, 2)
void linear_relu_splitk(const float* __restrict__ ch,
                        const __hip_bfloat16* __restrict__ w2,
                        const float* __restrict__ lin_b,
                        __hip_bfloat16* __restrict__ out1) {
  __shared__ float red[8 * 16 * NP];  // [w][row][col], 57344 B
  const int tid = threadIdx.x;
  const int w = tid >> 6, lane = tid & 63;
  const int l16 = lane & 15, bq = lane >> 4;
  const int kbase = w * 128;

  // B preload: breg[s][nt] = w2[nt*16+l16][kbase + s*32 + bq*8 ..+7]
  bf16x8 breg[4][7];
#pragma unroll
  for (int s = 0; s < 4; ++s)
#pragma unroll
    for (int nt = 0; nt < 7; ++nt)
      breg[s][nt] = *reinterpret_cast<const bf16x8*>(
          &w2[(nt * 16 + l16) * KP2 + kbase + s * 32 + bq * 8]);

  const int mbase = blockIdx.x * 64;

  // A-load for one M-tile into an 8-float4 buffer (batched issue).
  // Wave 7 (k 896..1023): s=0 vector (k<928 valid), s=1 masked scalars
  // (k 928..939 valid), s=2,3 zero (w2 rows there are zero anyway, but A
  // would be OOB -> just feed zeros; the 14 extra MFMAs add 0).
  auto issueA = [&](int m0, float4* buf) {
    const float* ar = ch + (long)(m0 + l16) * K1 + kbase + bq * 8;
    if (w < 7) {
#pragma unroll
      for (int s = 0; s < 4; ++s) {
        buf[2 * s]     = *reinterpret_cast<const float4*>(ar + s * 32);
        buf[2 * s + 1] = *reinterpret_cast<const float4*>(ar + s * 32 + 4);
      }
    } else {
      buf[0] = *reinterpret_cast<const float4*>(ar);
      buf[1] = *reinterpret_cast<const float4*>(ar + 4);
      float t[8];
#pragma unroll
      for (int j = 0; j < 8; ++j) {
        int k = 928 + bq * 8 + j;
        t[j] = (k < K1) ? ar[32 + j] : 0.f;  // predicated load, no OOB access
      }
      buf[2] = float4{t[0], t[1], t[2], t[3]};
      buf[3] = float4{t[4], t[5], t[6], t[7]};
      buf[4] = buf[5] = buf[6] = buf[7] = float4{0.f, 0.f, 0.f, 0.f};
    }
  };

  float4 a0[8], a1[8];
  issueA(mbase, a0);

#pragma unroll
  for (int i = 0; i < 4; ++i) {
    float4* cur = (i & 1) ? a1 : a0;
    float4* nxt = (i & 1) ? a0 : a1;
    if (i < 3) issueA(mbase + (i + 1) * 16, nxt);  // prefetch next tile

    f32x4 acc[7] = {};
#pragma unroll
    for (int s = 0; s < 4; ++s) {
      float4 lo = cur[2 * s], hi = cur[2 * s + 1];
      bf16x8 a = bf16x8{f2b(lo.x), f2b(lo.y), f2b(lo.z), f2b(lo.w),
                        f2b(hi.x), f2b(hi.y), f2b(hi.z), f2b(hi.w)};
#pragma unroll
      for (int nt = 0; nt < 7; ++nt) acc[nt] = MFMA16(a, breg[s][nt], acc[nt]);
    }

    // scatter partials to LDS: red[w][bq*4+r][nt*16+l16]
#pragma unroll
    for (int nt = 0; nt < 7; ++nt)
#pragma unroll
      for (int r = 0; r < 4; ++r)
        red[(w * 16 + bq * 4 + r) * NP + nt * 16 + l16] = acc[nt][r];
    __syncthreads();

    const int m0 = mbase + i * 16;
    if (tid < 448) {
      const int col = tid % NP;
      const int rb = (tid / NP) * 4;
      const float bias = (col < 100) ? lin_b[col] : 0.f;
#pragma unroll
      for (int r = 0; r < 4; ++r) {
        float s = 0.f;
#pragma unroll
        for (int ww = 0; ww < 8; ++ww) s += red[(ww * 16 + rb + r) * NP + col];
        float v = fmaxf(s + bias, 0.f);
        out1[(m0 + rb + r) * OUT1_LD + col] = __float2bfloat16((col < 100) ? v : 0.f);
      }
    } else {
      // zero the K-pad cols 112..127 (xg GEMM reads K=128)
      const int t2 = tid - 448;
      const int row = t2 >> 2, c0 = 112 + (t2 & 3) * 4;
#pragma unroll
      for (int q = 0; q < 4; ++q)
        out1[(m0 + row) * OUT1_LD + c0 + q] = __float2bfloat16(0.f);
    }
    __syncthreads();
  }
}

// ---------------------------------------------------------------------------
// Phase 2a: xg[m][g] = out1[m][:] @ bw2[g][:]^T + (b_bih[g]+b_bhh[g]), fp32.
// K=128 (zero padded), 4 N-tiles, weights straight from L2 (16 KB).
// ---------------------------------------------------------------------------
__global__ __launch_bounds__(256)
void xg_mfma(const __hip_bfloat16* __restrict__ out1,
             const __hip_bfloat16* __restrict__ bw2,
             const float* __restrict__ bih,
             const float* __restrict__ bhh,
             float* __restrict__ xg) {
  const int tid = threadIdx.x;
  const int wave = tid >> 6, lane = tid & 63;
  const int l16 = lane & 15, bq = lane >> 4;
  const int m0 = blockIdx.x * 64 + wave * 16;
  const int arow = (m0 + l16) * OUT1_LD;
  f32x4 acc[4] = {};
#pragma unroll
  for (int s = 0; s < 4; ++s) {
    const int k0 = s * 32;
    bf16x8 a = *reinterpret_cast<const bf16x8*>(&out1[arow + k0 + bq * 8]);
#pragma unroll
    for (int nt = 0; nt < 4; ++nt) {
      bf16x8 b = *reinterpret_cast<const bf16x8*>(&bw2[(nt * 16 + l16) * 128 + k0 + bq * 8]);
      acc[nt] = MFMA16(a, b, acc[nt]);
    }
  }
  const int mb = m0 + bq * 4;
#pragma unroll
  for (int nt = 0; nt < 4; ++nt) {
    const int g = nt * 16 + l16;
    const float bias = bih[g] + bhh[g];
#pragma unroll
    for (int r = 0; r < 4; ++r) xg[(mb + r) * 64 + g] = acc[nt][r] + bias;
  }
}

// ---------------------------------------------------------------------------
// Phase 2b: beats LSTM, barrier-free. One wave per sequence (gates=64=wave).
// h-state replicated in all lanes via __shfl; x prefetched for all 8 steps.
// Gate order i,f,g,o (PyTorch). fp32 recurrence; fp32 stores to d_out.
// ---------------------------------------------------------------------------
__global__ __launch_bounds__(256)
void beats_lstm(const float* __restrict__ xg,
                const float* __restrict__ whh,
                float* __restrict__ beats) {
  const int lane = threadIdx.x & 63;
  const int seq = blockIdx.x * 4 + (threadIdx.x >> 6);
  const int cell = lane & 15;
  float wr[16];
#pragma unroll
  for (int u = 0; u < 16; ++u) wr[u] = whh[lane * 16 + u];
  const float* xs = xg + seq * 512;
  float xv[8];
#pragma unroll
  for (int t = 0; t < 8; ++t) xv[t] = xs[t * 64 + lane];
  float h[16];
#pragma unroll
  for (int u = 0; u < 16; ++u) h[u] = 0.f;
  float c = 0.f;
#pragma unroll
  for (int t = 0; t < 8; ++t) {
    float pre = xv[t];
#pragma unroll
    for (int u = 0; u < 16; ++u) pre += wr[u] * h[u];
    float act = (lane >= 32 && lane < 48) ? tanhfast(pre) : sigf(pre);
    float gi = __shfl(act, cell);
    float gf = __shfl(act, cell + 16);
    float gg = __shfl(act, cell + 32);
    float go = __shfl(act, cell + 48);
    c = gf * c + gi * gg;          // lane j's c is cell (j&15), replicated 4x
    float hn = go * tanhfast(c);
#pragma unroll
    for (int u = 0; u < 16; ++u) h[u] = __shfl(hn, u);
    if (lane < 16) beats[seq * 128 + t * 16 + lane] = hn;
  }
}

// ---------------------------------------------------------------------------
// Phase 3: bars biLSTM. 1024 seqs, T=4(beats), H=32. Block = 1 seq,
// 256 threads = 2 dirs x 128 gates. Reads last-frac beats h from d_out (fp32).
// fwd half -> cols 0..31, bwd half -> cols 32..63 (concat order).
// ---------------------------------------------------------------------------
__global__ __launch_bounds__(256)
void bars_bilstm(const float* __restrict__ fwih, const float* __restrict__ fwhh,
                 const float* __restrict__ fbih, const float* __restrict__ fbhh,
                 const float* __restrict__ rwih, const float* __restrict__ rwhh,
                 const float* __restrict__ rbih, const float* __restrict__ rbhh,
                 const float* __restrict__ beats,
                 float* __restrict__ bars) {
  const int tid = threadIdx.x;
  const int dir = tid >> 7, g = tid & 127;
  const int n = blockIdx.x;
  const float* wih = dir ? rwih : fwih;
  const float* whh = dir ? rwhh : fwhh;
  const float bias = dir ? (rbih[g] + rbhh[g]) : (fbih[g] + fbhh[g]);
  float wi[16], wh[32];
#pragma unroll
  for (int u = 0; u < 16; ++u) wi[u] = wih[g * 16 + u];
#pragma unroll
  for (int u = 0; u < 32; ++u) wh[u] = whh[g * 32 + u];
  __shared__ float xbuf[2][16];
  __shared__ float hbuf[2][32];
  __shared__ float gact[2][128];
  float c = 0.f;
  if (g < 32) hbuf[dir][g] = 0.f;
  __syncthreads();
  for (int t = 0; t < 4; ++t) {
    const int tt = dir ? (3 - t) : t;
    if (g < 16) xbuf[dir][g] = beats[((n * 4 + tt) * 8 + 7) * 16 + g];
    __syncthreads();
    float pre = bias;
#pragma unroll
    for (int u = 0; u < 16; ++u) pre += wi[u] * xbuf[dir][u];
#pragma unroll
    for (int u = 0; u < 32; ++u) pre += wh[u] * hbuf[dir][u];
    gact[dir][g] = (g >= 64 && g < 96) ? tanhfast(pre) : sigf(pre);
    __syncthreads();
    if (g < 32) {
      c = gact[dir][32 + g] * c + gact[dir][g] * gact[dir][64 + g];
      float hn = gact[dir][96 + g] * tanhfast(c);
      hbuf[dir][g] = hn;
      bars[(n * 4 + tt) * 64 + dir * 32 + g] = hn;
    }
    __syncthreads();
  }
}

extern "C" void kernel_launch(void* const* d_in, const int* in_sizes, int n_in,
                              void* d_out, int out_size, void* d_ws, size_t ws_size,
                              hipStream_t stream) {
  const float* ch    = (const float*)d_in[0];
  const float* lin_w = (const float*)d_in[1];
  const float* lin_b = (const float*)d_in[2];
  const float* b_wih = (const float*)d_in[3];
  const float* b_whh = (const float*)d_in[4];
  const float* b_bih = (const float*)d_in[5];
  const float* b_bhh = (const float*)d_in[6];
  const float* f_wih = (const float*)d_in[7];
  const float* f_whh = (const float*)d_in[8];
  const float* f_bih = (const float*)d_in[9];
  const float* f_bhh = (const float*)d_in[10];
  const float* r_wih = (const float*)d_in[11];
  const float* r_whh = (const float*)d_in[12];
  const float* r_bih = (const float*)d_in[13];
  const float* r_bhh = (const float*)d_in[14];

  char* ws = (char*)d_ws;
  __hip_bfloat16* w2   = (__hip_bfloat16*)ws;             // 112*1024*2  = 229376 B
  __hip_bfloat16* bw2  = (__hip_bfloat16*)(ws + 229376);  // 64*128*2    = 16384 B
  __hip_bfloat16* out1 = (__hip_bfloat16*)(ws + 245760);  // 32768*128*2 = 8388608 B
  float*          xg   = (float*)(ws + 8634368);          // 32768*64*4  = 8388608 B
  float*          out  = (float*)d_out;

  prep_kernel<<<480, 256, 0, stream>>>(lin_w, b_wih, w2, bw2);
  linear_relu_splitk<<<512, 512, 0, stream>>>(ch, w2, lin_b, out1);
  xg_mfma<<<512, 256, 0, stream>>>(out1, bw2, b_bih, b_bhh, xg);
  beats_lstm<<<1024, 256, 0, stream>>>(xg, b_whh, out);
  bars_bilstm<<<1024, 256, 0, stream>>>(f_wih, f_whh, f_bih, f_bhh,
                                        r_wih, r_whh, r_bih, r_bhh,
                                        out, out + 524288);
}

// Round 6
// 240.339 us; speedup vs baseline: 1.1214x; 1.0166x over previous
//
#include <hip/hip_runtime.h>
#include <hip/hip_bf16.h>

typedef float f32x4 __attribute__((ext_vector_type(4)));
typedef short bf16x8 __attribute__((ext_vector_type(8)));

#define MFMA16(a, b, c) __builtin_amdgcn_mfma_f32_16x16x32_bf16(a, b, c, 0, 0, 0)

// Problem constants
constexpr int K1  = 940;    // IN_F
constexpr int KP2 = 1024;   // K padded to 8 chunks of 128
constexpr int NP  = 112;    // N=100 padded to 7 tiles of 16
constexpr int OSL = 136;    // out_s LDS row stride (bf16): 272B -> 2-way banks

__device__ __forceinline__ float sigf(float x) { return 1.f / (1.f + __expf(-x)); }
__device__ __forceinline__ float tanhfast(float x) { return 2.f / (1.f + __expf(-2.f * x)) - 1.f; }

__device__ __forceinline__ short f2b(float x) {
  __hip_bfloat16 b = __float2bfloat16(x);
  return *reinterpret_cast<short*>(&b);
}

// ---------------------------------------------------------------------------
// Prep: fold swapaxes(-1,-2) into the weights, convert fp32->bf16, zero-pad.
// w2[n][k] (n<112, k<1024) = bf16(lin_w[n][f]), k=c10*94+c2*47+c47,
// f=c10*94+c47*2+c2; zero outside n<100,k<940.
// bw2[g][k] = bf16(b_wih[g][k]) zero-padded K 100->128.
// ---------------------------------------------------------------------------
__global__ void prep_kernel(const float* __restrict__ lin_w,
                            const float* __restrict__ b_wih,
                            __hip_bfloat16* __restrict__ w2,
                            __hip_bfloat16* __restrict__ bw2) {
  int idx = blockIdx.x * 256 + threadIdx.x;
  if (idx < NP * KP2) {
    int n = idx >> 10, k = idx & 1023;
    float v = 0.f;
    if (n < 100 && k < K1) {
      int c10 = k / 94, rem = k - c10 * 94;
      int c2 = rem / 47, c47 = rem - c2 * 47;
      int f = c10 * 94 + c47 * 2 + c2;
      v = lin_w[n * K1 + f];
    }
    w2[idx] = __float2bfloat16(v);
  } else {
    int i2 = idx - NP * KP2;
    if (i2 < 64 * 128) {
      int g = i2 >> 7, k = i2 & 127;
      bw2[i2] = __float2bfloat16((k < 100) ? b_wih[g * 100 + k] : 0.f);
    }
  }
}

// ---------------------------------------------------------------------------
// Mega-fused: linear+relu (split-K-8 MFMA, B in registers) -> xg GEMM (from
// LDS) -> beats LSTM (8 waves = 8 seqs, shfl recurrence). One block = 64 GEMM
// rows = 8 complete frac-sequences. out1/xg never touch HBM; only the 2 MB
// beats tensor is written.
// ---------------------------------------------------------------------------
__global__ __launch_bounds__(512, 2)
void fused_encoder(const float* __restrict__ ch,
                   const __hip_bfloat16* __restrict__ w2,
                   const float* __restrict__ lin_b,
                   const __hip_bfloat16* __restrict__ bw2,
                   const float* __restrict__ bih,
                   const float* __restrict__ bhh,
                   const float* __restrict__ whh,
                   float* __restrict__ beats) {
  __shared__ float red[8 * 16 * NP];                         // 57344 B
  __shared__ __align__(16) __hip_bfloat16 out_s[64 * OSL];   // 17408 B
  __shared__ float xg_s[64 * 65];                            // 16640 B
  const int tid = threadIdx.x;
  const int w = tid >> 6, lane = tid & 63;
  const int l16 = lane & 15, bq = lane >> 4;
  const int kbase = w * 128;

  // ---- Phase A: split-K GEMM. B preload: 28 fragments in registers. ----
  bf16x8 breg[4][7];
#pragma unroll
  for (int s = 0; s < 4; ++s)
#pragma unroll
    for (int nt = 0; nt < 7; ++nt)
      breg[s][nt] = *reinterpret_cast<const bf16x8*>(
          &w2[(nt * 16 + l16) * KP2 + kbase + s * 32 + bq * 8]);

  const int mbase = blockIdx.x * 64;

  // Wave 7 (k 896..1023): s=0 vector, s=1 masked scalars (k<940), s=2,3 zero.
  auto issueA = [&](int m0, float4* buf) {
    const float* ar = ch + (long)(m0 + l16) * K1 + kbase + bq * 8;
    if (w < 7) {
#pragma unroll
      for (int s = 0; s < 4; ++s) {
        buf[2 * s]     = *reinterpret_cast<const float4*>(ar + s * 32);
        buf[2 * s + 1] = *reinterpret_cast<const float4*>(ar + s * 32 + 4);
      }
    } else {
      buf[0] = *reinterpret_cast<const float4*>(ar);
      buf[1] = *reinterpret_cast<const float4*>(ar + 4);
      float t[8];
#pragma unroll
      for (int j = 0; j < 8; ++j) {
        int k = 928 + bq * 8 + j;
        t[j] = (k < K1) ? ar[32 + j] : 0.f;
      }
      buf[2] = float4{t[0], t[1], t[2], t[3]};
      buf[3] = float4{t[4], t[5], t[6], t[7]};
      buf[4] = buf[5] = buf[6] = buf[7] = float4{0.f, 0.f, 0.f, 0.f};
    }
  };

  float4 a0[8], a1[8];
  issueA(mbase, a0);

#pragma unroll
  for (int i = 0; i < 4; ++i) {
    float4* cur = (i & 1) ? a1 : a0;
    float4* nxt = (i & 1) ? a0 : a1;
    if (i < 3) issueA(mbase + (i + 1) * 16, nxt);  // in flight during reduce

    f32x4 acc[7] = {};
#pragma unroll
    for (int s = 0; s < 4; ++s) {
      float4 lo = cur[2 * s], hi = cur[2 * s + 1];
      bf16x8 a = bf16x8{f2b(lo.x), f2b(lo.y), f2b(lo.z), f2b(lo.w),
                        f2b(hi.x), f2b(hi.y), f2b(hi.z), f2b(hi.w)};
#pragma unroll
      for (int nt = 0; nt < 7; ++nt) acc[nt] = MFMA16(a, breg[s][nt], acc[nt]);
    }

    // scatter partials: red[w][bq*4+r][nt*16+l16]
#pragma unroll
    for (int nt = 0; nt < 7; ++nt)
#pragma unroll
      for (int r = 0; r < 4; ++r)
        red[(w * 16 + bq * 4 + r) * NP + nt * 16 + l16] = acc[nt][r];
    __syncthreads();

    // split-K reduce + bias + relu -> out_s (bf16, padded stride)
    if (tid < 448) {
      const int col = tid % NP;
      const int rb = (tid / NP) * 4;
      const float bias = (col < 100) ? lin_b[col] : 0.f;
#pragma unroll
      for (int r = 0; r < 4; ++r) {
        float s = 0.f;
#pragma unroll
        for (int ww = 0; ww < 8; ++ww) s += red[(ww * 16 + rb + r) * NP + col];
        float v = fmaxf(s + bias, 0.f);
        out_s[(i * 16 + rb + r) * OSL + col] = __float2bfloat16((col < 100) ? v : 0.f);
      }
    } else {
      const int t2 = tid - 448;               // zero K-pad cols 112..127
      const int row = t2 >> 2, c0 = 112 + (t2 & 3) * 4;
#pragma unroll
      for (int q = 0; q < 4; ++q)
        out_s[(i * 16 + row) * OSL + c0 + q] = __float2bfloat16(0.f);
    }
    __syncthreads();
  }

  // ---- Phase B: xg[64 rows][64 gates] = out_s @ bw2^T + (bih+bhh). ----
  // 16 (row-tile x gate-tile) combos over 8 waves: 2 gate-tiles each.
  {
    const int rt = w >> 1, gt0 = (w & 1) * 2;
    bf16x8 av[4];
#pragma unroll
    for (int s = 0; s < 4; ++s)
      av[s] = *reinterpret_cast<const bf16x8*>(&out_s[(rt * 16 + l16) * OSL + s * 32 + bq * 8]);
    f32x4 xacc[2] = {{0.f, 0.f, 0.f, 0.f}, {0.f, 0.f, 0.f, 0.f}};
#pragma unroll
    for (int g2 = 0; g2 < 2; ++g2) {
      const int gt = gt0 + g2;
#pragma unroll
      for (int s = 0; s < 4; ++s) {
        bf16x8 b = *reinterpret_cast<const bf16x8*>(&bw2[(gt * 16 + l16) * 128 + s * 32 + bq * 8]);
        xacc[g2] = MFMA16(av[s], b, xacc[g2]);
      }
    }
#pragma unroll
    for (int g2 = 0; g2 < 2; ++g2) {
      const int gate = (gt0 + g2) * 16 + l16;
      const float bias = bih[gate] + bhh[gate];
#pragma unroll
      for (int r = 0; r < 4; ++r)
        xg_s[(rt * 16 + bq * 4 + r) * 65 + gate] = xacc[g2][r] + bias;
    }
  }
  __syncthreads();

  // ---- Phase C: beats LSTM. Wave w = sequence w (rows w*8..w*8+7). ----
  {
    const int cell = lane & 15;
    float wr[16];
#pragma unroll
    for (int u = 0; u < 16; ++u) wr[u] = whh[lane * 16 + u];
    float xv[8];
#pragma unroll
    for (int t = 0; t < 8; ++t) xv[t] = xg_s[(w * 8 + t) * 65 + lane];
    float h[16];
#pragma unroll
    for (int u = 0; u < 16; ++u) h[u] = 0.f;
    float c = 0.f;
    const int seq = blockIdx.x * 8 + w;
#pragma unroll
    for (int t = 0; t < 8; ++t) {
      float pre = xv[t];
#pragma unroll
      for (int u = 0; u < 16; ++u) pre += wr[u] * h[u];
      float act = (lane >= 32 && lane < 48) ? tanhfast(pre) : sigf(pre);
      float gi = __shfl(act, cell);
      float gf = __shfl(act, cell + 16);
      float gg = __shfl(act, cell + 32);
      float go = __shfl(act, cell + 48);
      c = gf * c + gi * gg;
      float hn = go * tanhfast(c);
#pragma unroll
      for (int u = 0; u < 16; ++u) h[u] = __shfl(hn, u);
      if (lane < 16) beats[seq * 128 + t * 16 + lane] = hn;
    }
  }
}

// ---------------------------------------------------------------------------
// Phase 3: bars biLSTM. 1024 seqs, T=4(beats), H=32. Block = 1 seq,
// 256 threads = 2 dirs x 128 gates. Reads last-frac beats h from d_out (fp32).
// fwd half -> cols 0..31, bwd half -> cols 32..63 (concat order).
// ---------------------------------------------------------------------------
__global__ __launch_bounds__(256)
void bars_bilstm(const float* __restrict__ fwih, const float* __restrict__ fwhh,
                 const float* __restrict__ fbih, const float* __restrict__ fbhh,
                 const float* __restrict__ rwih, const float* __restrict__ rwhh,
                 const float* __restrict__ rbih, const float* __restrict__ rbhh,
                 const float* __restrict__ beats,
                 float* __restrict__ bars) {
  const int tid = threadIdx.x;
  const int dir = tid >> 7, g = tid & 127;
  const int n = blockIdx.x;
  const float* wih = dir ? rwih : fwih;
  const float* whh = dir ? rwhh : fwhh;
  const float bias = dir ? (rbih[g] + rbhh[g]) : (fbih[g] + fbhh[g]);
  float wi[16], wh[32];
#pragma unroll
  for (int u = 0; u < 16; ++u) wi[u] = wih[g * 16 + u];
#pragma unroll
  for (int u = 0; u < 32; ++u) wh[u] = whh[g * 32 + u];
  __shared__ float xbuf[2][16];
  __shared__ float hbuf[2][32];
  __shared__ float gact[2][128];
  float c = 0.f;
  if (g < 32) hbuf[dir][g] = 0.f;
  __syncthreads();
  for (int t = 0; t < 4; ++t) {
    const int tt = dir ? (3 - t) : t;
    if (g < 16) xbuf[dir][g] = beats[((n * 4 + tt) * 8 + 7) * 16 + g];
    __syncthreads();
    float pre = bias;
#pragma unroll
    for (int u = 0; u < 16; ++u) pre += wi[u] * xbuf[dir][u];
#pragma unroll
    for (int u = 0; u < 32; ++u) pre += wh[u] * hbuf[dir][u];
    gact[dir][g] = (g >= 64 && g < 96) ? tanhfast(pre) : sigf(pre);
    __syncthreads();
    if (g < 32) {
      c = gact[dir][32 + g] * c + gact[dir][g] * gact[dir][64 + g];
      float hn = gact[dir][96 + g] * tanhfast(c);
      hbuf[dir][g] = hn;
      bars[(n * 4 + tt) * 64 + dir * 32 + g] = hn;
    }
    __syncthreads();
  }
}

extern "C" void kernel_launch(void* const* d_in, const int* in_sizes, int n_in,
                              void* d_out, int out_size, void* d_ws, size_t ws_size,
                              hipStream_t stream) {
  const float* ch    = (const float*)d_in[0];
  const float* lin_w = (const float*)d_in[1];
  const float* lin_b = (const float*)d_in[2];
  const float* b_wih = (const float*)d_in[3];
  const float* b_whh = (const float*)d_in[4];
  const float* b_bih = (const float*)d_in[5];
  const float* b_bhh = (const float*)d_in[6];
  const float* f_wih = (const float*)d_in[7];
  const float* f_whh = (const float*)d_in[8];
  const float* f_bih = (const float*)d_in[9];
  const float* f_bhh = (const float*)d_in[10];
  const float* r_wih = (const float*)d_in[11];
  const float* r_whh = (const float*)d_in[12];
  const float* r_bih = (const float*)d_in[13];
  const float* r_bhh = (const float*)d_in[14];

  char* ws = (char*)d_ws;
  __hip_bfloat16* w2  = (__hip_bfloat16*)ws;             // 112*1024*2 = 229376 B
  __hip_bfloat16* bw2 = (__hip_bfloat16*)(ws + 229376);  // 64*128*2   = 16384 B
  float*          out = (float*)d_out;

  prep_kernel<<<480, 256, 0, stream>>>(lin_w, b_wih, w2, bw2);
  fused_encoder<<<512, 512, 0, stream>>>(ch, w2, lin_b, bw2, b_bih, b_bhh,
                                         b_whh, out);
  bars_bilstm<<<1024, 256, 0, stream>>>(f_wih, f_whh, f_bih, f_bhh,
                                        r_wih, r_whh, r_bih, r_bhh,
                                        out, out + 524288);
}